// Round 7
// baseline (7779.771 us; speedup 1.0000x reference)
//
#include <hip/hip_runtime.h>
#include <stdint.h>

// T=1024, B=32, D=H=1024.  M = T*B = 32768.
typedef float  f32x4  __attribute__((ext_vector_type(4)));
typedef short  bf16x8 __attribute__((ext_vector_type(8)));
typedef unsigned int u32x4 __attribute__((ext_vector_type(4)));

__device__ __forceinline__ unsigned short f2bf(float f) {
  union { float f; unsigned u; } v; v.f = f;
  unsigned r = v.u + 0x7fffu + ((v.u >> 16) & 1u);   // RNE, inputs are finite
  return (unsigned short)(r >> 16);
}
__device__ __forceinline__ float bf2f(unsigned short s) {
  union { unsigned u; float f; } v; v.u = ((unsigned)s) << 16; return v.f;
}
__device__ __forceinline__ bf16x8 pack8(float4 a, float4 b) {
  bf16x8 v;
  v[0]=(short)f2bf(a.x); v[1]=(short)f2bf(a.y); v[2]=(short)f2bf(a.z); v[3]=(short)f2bf(a.w);
  v[4]=(short)f2bf(b.x); v[5]=(short)f2bf(b.y); v[6]=(short)f2bf(b.z); v[7]=(short)f2bf(b.w);
  return v;
}
__device__ __forceinline__ f32x4 mfma16(bf16x8 a, bf16x8 b, f32x4 c) {
  return __builtin_amdgcn_mfma_f32_16x16x32_bf16(a, b, c, 0, 0, 0);
}
// fast tanh: 1 - 2/(exp(2y)+1); v_exp/v_rcp are ~1ulp, saturates correctly.
__device__ __forceinline__ float fast_tanh(float y) {
  return 1.0f - 2.0f * __builtin_amdgcn_rcpf(__expf(2.0f * y) + 1.0f);
}

// ---------------------------------------------------------------------------
// Phase 1 (unchanged, known-good): wx = x@Wx^T + bias -> d_out (fp32);
// delta = sigmoid(x@Wd^T + b_delta) -> ws (bf16).
// ---------------------------------------------------------------------------
__global__ __launch_bounds__(256) void proj_kernel(
    const float* __restrict__ x,  const float* __restrict__ Wx,
    const float* __restrict__ Wd, const float* __restrict__ bias,
    const float* __restrict__ bd, float* __restrict__ wx_out,
    unsigned short* __restrict__ delta_out)
{
  __shared__ __align__(16) unsigned short lA[128 * 40];
  __shared__ __align__(16) unsigned short lB[128 * 40];

  const int tid  = threadIdx.x;
  const int lane = tid & 63;
  const int wv   = tid >> 6;
  const int wm   = (wv >> 1) * 64;
  const int wn   = (wv & 1) * 64;
  const int l15  = lane & 15, lhi = lane >> 4;

  const int  bm    = blockIdx.x;
  const int  bn    = blockIdx.y;
  const bool isd   = bn >= 8;
  const float* W   = isd ? Wd : Wx;
  const int  ncol0 = (bn & 7) * 128;
  const int  row0  = bm * 128;

  const int srow = tid >> 1;
  const int scol = (tid & 1) * 16;

  f32x4 acc[4][4] = {};

  for (int k0 = 0; k0 < 1024; k0 += 32) {
    const float* pa = x + (size_t)(row0 + srow) * 1024 + (k0 + scol);
    const float* pb = W + (size_t)(ncol0 + srow) * 1024 + (k0 + scol);
    float4 a0 = *(const float4*)(pa + 0), a1 = *(const float4*)(pa + 4);
    float4 a2 = *(const float4*)(pa + 8), a3 = *(const float4*)(pa + 12);
    float4 b0 = *(const float4*)(pb + 0), b1 = *(const float4*)(pb + 4);
    float4 b2 = *(const float4*)(pb + 8), b3 = *(const float4*)(pb + 12);

    *(bf16x8*)&lA[srow * 40 + scol]     = pack8(a0, a1);
    *(bf16x8*)&lA[srow * 40 + scol + 8] = pack8(a2, a3);
    *(bf16x8*)&lB[srow * 40 + scol]     = pack8(b0, b1);
    *(bf16x8*)&lB[srow * 40 + scol + 8] = pack8(b2, b3);
    __syncthreads();

    bf16x8 af[4], bfr[4];
    #pragma unroll
    for (int i = 0; i < 4; ++i) {
      af[i]  = *(const bf16x8*)&lA[(wm + i * 16 + l15) * 40 + lhi * 8];
      bfr[i] = *(const bf16x8*)&lB[(wn + i * 16 + l15) * 40 + lhi * 8];
    }
    #pragma unroll
    for (int i = 0; i < 4; ++i)
      #pragma unroll
      for (int j = 0; j < 4; ++j)
        acc[i][j] = mfma16(af[i], bfr[j], acc[i][j]);
    __syncthreads();
  }

  #pragma unroll
  for (int i = 0; i < 4; ++i) {
    const int rbase = row0 + wm + i * 16 + lhi * 4;
    #pragma unroll
    for (int j = 0; j < 4; ++j) {
      const int col = ncol0 + wn + j * 16 + l15;
      #pragma unroll
      for (int r = 0; r < 4; ++r) {
        const size_t idx = (size_t)(rbase + r) * 1024 + col;
        const float v = acc[i][j][r];
        if (!isd) {
          wx_out[idx] = v + bias[col];
        } else {
          const float s = 1.0f / (1.0f + expf(-(v + bd[col])));
          delta_out[idx] = f2bf(s);
        }
      }
    }
  }
}

// ---------------------------------------------------------------------------
// Phase 2: persistent recurrence with SELF-VALIDATING TAGGED h exchange.
// grid = 16 WGs x 256 thr: blockIdx = bg*8 + chunk (bg = batch group of 16).
// Exchange unit = one aligned dword per (batch,col): hi16 = bf16(h), lo16 =
// step tag.  Aligned dword stores are HW-atomic -> tag valid <=> value valid;
// producers fire-and-forget (NO ack drain, NO flags).  Consumers poll their
// own 256B staging region (16x dwordx4 sc0 sc1) until all 64 tags == t+1 —
// the poll IS the staged load.  Tag buffers (2 parity x 16x1024 dwords per
// bg) are zeroed by an in-graph memset each launch, so stale tags from prior
// replays can never false-match (targets start at 1).  Double-buffer reuse
// within a run can't false-match either (parity-p at step t wants t+1; stale
// entries hold t-1).  No inter-WG barriers anywhere; liveness by induction
// on unconditional publishes (round-4 argument, fewer moving parts).
// ---------------------------------------------------------------------------
__global__ __launch_bounds__(256, 1) void rnn_kernel(
    const float* __restrict__ R, const float* __restrict__ h0,
    float* __restrict__ out, const unsigned short* __restrict__ delta,
    unsigned int* __restrict__ tg)
{
  __shared__ __align__(16) unsigned short hs[2][16384];   // 2 x 32KB bf16 tile

  const int tid  = threadIdx.x;
  const int lane = tid & 63;
  const int wv   = tid >> 6;
  const int l15  = lane & 15, lhi = lane >> 4;
  const int chunk = blockIdx.x & 7;
  const int bg    = blockIdx.x >> 3;
  const int B0    = bg * 16;
  const int cb    = chunk * 128 + wv * 32;
  unsigned int* tgbg = tg + (size_t)bg * 32768;   // 2 parity x 16*1024 dwords

  // R fragments as A-operand: ra[nt][kt] = R[j=cb+nt*16+l15][kt*32+lhi*8 ..+7]
  bf16x8 ra[2][32];
  #pragma unroll
  for (int nt = 0; nt < 2; ++nt) {
    const float* rrow = R + (size_t)(cb + nt * 16 + l15) * 1024 + lhi * 8;
    #pragma unroll
    for (int kt = 0; kt < 32; ++kt) {
      float4 u0 = *(const float4*)(rrow + kt * 32);
      float4 u1 = *(const float4*)(rrow + kt * 32 + 4);
      ra[nt][kt] = pack8(u0, u1);
    }
  }

  const int b = B0 + l15;                       // this lane's batch (C-col)
  const int j0[2] = { cb + lhi * 4, cb + 16 + lhi * 4 };

  // init h; publish h0 into parity-0 with tag=1 (fire-and-forget)
  float hloc[2][4];
  #pragma unroll
  for (int nt = 0; nt < 2; ++nt) {
    const f32x4 hv = *(const f32x4*)(h0 + (size_t)b * 1024 + j0[nt]);
    #pragma unroll
    for (int r = 0; r < 4; ++r) {
      hloc[nt][r] = hv[r];
      const unsigned dw = ((unsigned)f2bf(hv[r]) << 16) | 1u;
      __hip_atomic_store(tgbg + (size_t)l15 * 1024 + j0[nt] + r, dw,
                         __ATOMIC_RELAXED, __HIP_MEMORY_SCOPE_AGENT);
    }
  }

  // staging map: thread i -> local row (i&15), 64-dword col-block (i>>4)
  const int lrow = tid & 15, cblk = tid >> 4;
  int swz[8];
  #pragma unroll
  for (int m = 0; m < 8; ++m)
    swz[m] = lrow * 2048 + ((cblk * 128 + m * 16) ^ ((lrow & 7) << 4));
  const int rbase_l = l15 * 2048;
  const int rxor    = (l15 & 7) << 4;

  for (int t = 0; t < 1024; ++t) {
    const unsigned int* tgin  = tgbg + (t & 1) * 16384;
    unsigned int*       tgout = tgbg + ((t & 1) ^ 1) * 16384;
    float*                outp = out + (size_t)t * 32768;
    const unsigned short* dp   = delta + (size_t)t * 32768;
    const unsigned tag = (unsigned)(t + 1) & 0xFFFFu;

    // Prefetch wx / delta (plain cached loads; drained by poll's vmcnt).
    f32x4 wx4[2]; unsigned long long d4[2];
    #pragma unroll
    for (int nt = 0; nt < 2; ++nt) {
      wx4[nt] = *(const f32x4*)(outp + (size_t)b * 1024 + j0[nt]);
      d4[nt]  = *(const unsigned long long*)(dp + (size_t)b * 1024 + j0[nt]);
    }

    // Fused poll+stage: re-load my 64 tagged dwords until every tag == t+1.
    const unsigned int* gp = tgin + (size_t)lrow * 1024 + cblk * 64;
    u32x4 w0,w1,w2,w3,w4,w5,w6,w7,w8,w9,w10,w11,w12,w13,w14,w15;
    for (;;) {
      asm volatile(
        "global_load_dwordx4 %0, %16, off sc0 sc1\n\t"
        "global_load_dwordx4 %1, %16, off offset:16 sc0 sc1\n\t"
        "global_load_dwordx4 %2, %16, off offset:32 sc0 sc1\n\t"
        "global_load_dwordx4 %3, %16, off offset:48 sc0 sc1\n\t"
        "global_load_dwordx4 %4, %16, off offset:64 sc0 sc1\n\t"
        "global_load_dwordx4 %5, %16, off offset:80 sc0 sc1\n\t"
        "global_load_dwordx4 %6, %16, off offset:96 sc0 sc1\n\t"
        "global_load_dwordx4 %7, %16, off offset:112 sc0 sc1\n\t"
        "global_load_dwordx4 %8, %16, off offset:128 sc0 sc1\n\t"
        "global_load_dwordx4 %9, %16, off offset:144 sc0 sc1\n\t"
        "global_load_dwordx4 %10, %16, off offset:160 sc0 sc1\n\t"
        "global_load_dwordx4 %11, %16, off offset:176 sc0 sc1\n\t"
        "global_load_dwordx4 %12, %16, off offset:192 sc0 sc1\n\t"
        "global_load_dwordx4 %13, %16, off offset:208 sc0 sc1\n\t"
        "global_load_dwordx4 %14, %16, off offset:224 sc0 sc1\n\t"
        "global_load_dwordx4 %15, %16, off offset:240 sc0 sc1\n\t"
        "s_waitcnt vmcnt(0)"
        : "=&v"(w0), "=&v"(w1), "=&v"(w2), "=&v"(w3),
          "=&v"(w4), "=&v"(w5), "=&v"(w6), "=&v"(w7),
          "=&v"(w8), "=&v"(w9), "=&v"(w10), "=&v"(w11),
          "=&v"(w12), "=&v"(w13), "=&v"(w14), "=&v"(w15)
        : "v"(gp)
        : "memory");
      unsigned a = 0;
      #define ACC4(W) { a |= (W[0]^tag); a |= (W[1]^tag); a |= (W[2]^tag); a |= (W[3]^tag); }
      ACC4(w0) ACC4(w1) ACC4(w2) ACC4(w3) ACC4(w4) ACC4(w5) ACC4(w6) ACC4(w7)
      ACC4(w8) ACC4(w9) ACC4(w10) ACC4(w11) ACC4(w12) ACC4(w13) ACC4(w14) ACC4(w15)
      #undef ACC4
      if ((a & 0xFFFFu) == 0u) break;
    }
    __builtin_amdgcn_sched_barrier(0);

    // Strip tags (value = hi16) and write swizzled LDS tile (8 x 16B).
    char* lb = (char*)&hs[t & 1][0];
    #define PACKW(m, A, B) {                                                  \
      u32x4 pk;                                                               \
      pk[0] = (A[0] >> 16) | (A[1] & 0xFFFF0000u);                            \
      pk[1] = (A[2] >> 16) | (A[3] & 0xFFFF0000u);                            \
      pk[2] = (B[0] >> 16) | (B[1] & 0xFFFF0000u);                            \
      pk[3] = (B[2] >> 16) | (B[3] & 0xFFFF0000u);                            \
      *(u32x4*)(lb + swz[m]) = pk; }
    PACKW(0, w0,  w1)  PACKW(1, w2,  w3)  PACKW(2, w4,  w5)  PACKW(3, w6,  w7)
    PACKW(4, w8,  w9)  PACKW(5, w10, w11) PACKW(6, w12, w13) PACKW(7, w14, w15)
    #undef PACKW
    __syncthreads();

    // y^T = R_chunk @ h^T  (B-frags from LDS, 4-way acc rotation)
    const char* lr = lb + rbase_l;
    f32x4 acc[2][4] = {};
    #pragma unroll
    for (int kt = 0; kt < 32; ++kt) {
      const bf16x8 a = *(const bf16x8*)(lr + ((kt * 64 + lhi * 16) ^ rxor));
      acc[0][kt & 3] = mfma16(ra[0][kt], a, acc[0][kt & 3]);
      acc[1][kt & 3] = mfma16(ra[1][kt], a, acc[1][kt & 3]);
    }

    // blend; publish tagged h (fire-and-forget), THEN fat fp32 out stores.
    const unsigned ntag = (unsigned)(t + 2) & 0xFFFFu;
    f32x4 o[2];
    #pragma unroll
    for (int nt = 0; nt < 2; ++nt) {
      const f32x4 y = (acc[nt][0] + acc[nt][1]) + (acc[nt][2] + acc[nt][3]) + wx4[nt];
      #pragma unroll
      for (int r = 0; r < 4; ++r) {
        const float c = fast_tanh(y[r]);
        const float d = bf2f((unsigned short)(d4[nt] >> (16 * r)));
        const float h = hloc[nt][r];
        const float v = fmaf(d, c - h, h);
        hloc[nt][r] = v;
        o[nt][r] = v;
        const unsigned dw = ((unsigned)f2bf(v) << 16) | ntag;
        __hip_atomic_store(tgout + (size_t)l15 * 1024 + j0[nt] + r, dw,
                           __ATOMIC_RELAXED, __HIP_MEMORY_SCOPE_AGENT);
      }
    }
    #pragma unroll
    for (int nt = 0; nt < 2; ++nt)
      *(f32x4*)(outp + (size_t)b * 1024 + j0[nt]) = o[nt];
  }
}

// ---------------------------------------------------------------------------
extern "C" void kernel_launch(void* const* d_in, const int* in_sizes, int n_in,
                              void* d_out, int out_size, void* d_ws, size_t ws_size,
                              hipStream_t stream) {
  const float* x    = (const float*)d_in[0];
  const float* h0   = (const float*)d_in[1];
  const float* Wx   = (const float*)d_in[2];
  const float* R    = (const float*)d_in[3];
  const float* bias = (const float*)d_in[4];
  const float* Wd   = (const float*)d_in[5];
  const float* bd   = (const float*)d_in[6];
  float* out = (float*)d_out;

  // ws layout: [0,64MiB) delta bf16; tagged exchange at 64MiB+4KiB:
  // 2 bgs x 2 parity x 16x1024 dwords = 256KiB, zeroed in-graph each launch.
  unsigned short* delta_ws = (unsigned short*)d_ws;
  unsigned int*   tg       = (unsigned int*)((char*)d_ws + (64ull << 20) + 4096);

  hipMemsetAsync(tg, 0, 2ull * 2 * 16 * 1024 * 4, stream);

  dim3 pg(256, 16);
  proj_kernel<<<pg, 256, 0, stream>>>(x, Wx, Wd, bias, bd, out, delta_ws);
  rnn_kernel<<<16, 256, 0, stream>>>(R, h0, out, delta_ws, tg);
}

// Round 8
// 6204.034 us; speedup vs baseline: 1.2540x; 1.2540x over previous
//
#include <hip/hip_runtime.h>
#include <stdint.h>

// T=1024, B=32, D=H=1024.  M = T*B = 32768.
typedef float  f32x4  __attribute__((ext_vector_type(4)));
typedef short  bf16x8 __attribute__((ext_vector_type(8)));
typedef unsigned int u32x4 __attribute__((ext_vector_type(4)));

// Sync region: 8 groups x 33024B at ws+64MiB.
//   per group: Lbuf 16KB (2 parity x [4][1024] bf16) | Lflag 128B |
//              Gbuf 16KB | Gflag 128B
#define WS_SYNC_OFF (64ull << 20)
#define GRP_STRIDE  33024ull
#define LFLAG_OFF   16384
#define GBUF_OFF    16512
#define GFLAG_OFF   32896
#define SPIN_LIMIT  20000

__device__ __forceinline__ unsigned short f2bf(float f) {
  union { float f; unsigned u; } v; v.f = f;
  unsigned r = v.u + 0x7fffu + ((v.u >> 16) & 1u);   // RNE, inputs finite
  return (unsigned short)(r >> 16);
}
__device__ __forceinline__ float bf2f(unsigned short s) {
  union { unsigned u; float f; } v; v.u = ((unsigned)s) << 16; return v.f;
}
__device__ __forceinline__ bf16x8 pack8(float4 a, float4 b) {
  bf16x8 v;
  v[0]=(short)f2bf(a.x); v[1]=(short)f2bf(a.y); v[2]=(short)f2bf(a.z); v[3]=(short)f2bf(a.w);
  v[4]=(short)f2bf(b.x); v[5]=(short)f2bf(b.y); v[6]=(short)f2bf(b.z); v[7]=(short)f2bf(b.w);
  return v;
}
__device__ __forceinline__ unsigned long long pack4bf(float a, float b, float c, float d) {
  return (unsigned long long)f2bf(a) | ((unsigned long long)f2bf(b) << 16)
       | ((unsigned long long)f2bf(c) << 32) | ((unsigned long long)f2bf(d) << 48);
}
__device__ __forceinline__ f32x4 mfma16(bf16x8 a, bf16x8 b, f32x4 c) {
  return __builtin_amdgcn_mfma_f32_16x16x32_bf16(a, b, c, 0, 0, 0);
}
__device__ __forceinline__ float fast_tanh(float y) {
  return 1.0f - 2.0f * __builtin_amdgcn_rcpf(__expf(2.0f * y) + 1.0f);
}

__device__ __forceinline__ void st8_loc(void* p, unsigned long long v) {
  asm volatile("global_store_dwordx2 %0, %1, off sc0" :: "v"(p), "v"(v) : "memory");
}
__device__ __forceinline__ void st8_glb(void* p, unsigned long long v) {
  asm volatile("global_store_dwordx2 %0, %1, off sc0 sc1" :: "v"(p), "v"(v) : "memory");
}
__device__ __forceinline__ void st4_loc(void* p, unsigned v) {
  asm volatile("global_store_dword %0, %1, off sc0" :: "v"(p), "v"(v) : "memory");
}
__device__ __forceinline__ void st4_glb(void* p, unsigned v) {
  asm volatile("global_store_dword %0, %1, off sc0 sc1" :: "v"(p), "v"(v) : "memory");
}

// ---------------------------------------------------------------------------
// Phase 1 (unchanged, known-good): wx = x@Wx^T + bias -> d_out (fp32);
// delta = sigmoid(x@Wd^T + b_delta) -> ws (bf16).
// ---------------------------------------------------------------------------
__global__ __launch_bounds__(256) void proj_kernel(
    const float* __restrict__ x,  const float* __restrict__ Wx,
    const float* __restrict__ Wd, const float* __restrict__ bias,
    const float* __restrict__ bd, float* __restrict__ wx_out,
    unsigned short* __restrict__ delta_out)
{
  __shared__ __align__(16) unsigned short lA[128 * 40];
  __shared__ __align__(16) unsigned short lB[128 * 40];

  const int tid  = threadIdx.x;
  const int lane = tid & 63;
  const int wv   = tid >> 6;
  const int wm   = (wv >> 1) * 64;
  const int wn   = (wv & 1) * 64;
  const int l15  = lane & 15, lhi = lane >> 4;

  const int  bm    = blockIdx.x;
  const int  bn    = blockIdx.y;
  const bool isd   = bn >= 8;
  const float* W   = isd ? Wd : Wx;
  const int  ncol0 = (bn & 7) * 128;
  const int  row0  = bm * 128;

  const int srow = tid >> 1;
  const int scol = (tid & 1) * 16;

  f32x4 acc[4][4] = {};

  for (int k0 = 0; k0 < 1024; k0 += 32) {
    const float* pa = x + (size_t)(row0 + srow) * 1024 + (k0 + scol);
    const float* pb = W + (size_t)(ncol0 + srow) * 1024 + (k0 + scol);
    float4 a0 = *(const float4*)(pa + 0), a1 = *(const float4*)(pa + 4);
    float4 a2 = *(const float4*)(pa + 8), a3 = *(const float4*)(pa + 12);
    float4 b0 = *(const float4*)(pb + 0), b1 = *(const float4*)(pb + 4);
    float4 b2 = *(const float4*)(pb + 8), b3 = *(const float4*)(pb + 12);

    *(bf16x8*)&lA[srow * 40 + scol]     = pack8(a0, a1);
    *(bf16x8*)&lA[srow * 40 + scol + 8] = pack8(a2, a3);
    *(bf16x8*)&lB[srow * 40 + scol]     = pack8(b0, b1);
    *(bf16x8*)&lB[srow * 40 + scol + 8] = pack8(b2, b3);
    __syncthreads();

    bf16x8 af[4], bfr[4];
    #pragma unroll
    for (int i = 0; i < 4; ++i) {
      af[i]  = *(const bf16x8*)&lA[(wm + i * 16 + l15) * 40 + lhi * 8];
      bfr[i] = *(const bf16x8*)&lB[(wn + i * 16 + l15) * 40 + lhi * 8];
    }
    #pragma unroll
    for (int i = 0; i < 4; ++i)
      #pragma unroll
      for (int j = 0; j < 4; ++j)
        acc[i][j] = mfma16(af[i], bfr[j], acc[i][j]);
    __syncthreads();
  }

  #pragma unroll
  for (int i = 0; i < 4; ++i) {
    const int rbase = row0 + wm + i * 16 + lhi * 4;
    #pragma unroll
    for (int j = 0; j < 4; ++j) {
      const int col = ncol0 + wn + j * 16 + l15;
      #pragma unroll
      for (int r = 0; r < 4; ++r) {
        const size_t idx = (size_t)(rbase + r) * 1024 + col;
        const float v = acc[i][j][r];
        if (!isd) {
          wx_out[idx] = v + bias[col];
        } else {
          const float s = 1.0f / (1.0f + expf(-(v + bd[col])));
          delta_out[idx] = f2bf(s);
        }
      }
    }
  }
}

// ---------------------------------------------------------------------------
// Phase 2: 8 INDEPENDENT group-recurrences, one per blockIdx%8 class.
// Group g = 8 WGs {blockIdx%8==g} (round-robin -> same XCD), owns batches
// 4g..4g+3 completely: WG(chunk) computes output cols [128*chunk, +128) for
// those 4 batches; exchange = the group's 8KB h-slab.  No cross-group deps.
// Dual-path exchange:
//   local  : Lbuf/Lflag via sc0 only (L1 bypass; shared local L2 if peers
//            are co-XCD).  Consumers spin BOUNDED on Lflag.
//   global : Gbuf/Gflag via sc0sc1 (r4-proven chip-global path), published
//            unconditionally every step AFTER the local flag (off critical
//            path).  On local-spin timeout a WG permanently switches here.
// Placement is never detected, only exploited; wrong placement costs one
// ~3ms timeout then runs at r4 speed.  No unbounded wait on anything
// unverified.  Flags carry absolute step counts; flag lines are memset
// in-graph each launch (kernel-boundary acquire makes that visible).
// ---------------------------------------------------------------------------
__global__ __launch_bounds__(256, 1) void rnn_kernel(
    const float* __restrict__ R, const float* __restrict__ h0,
    float* __restrict__ out, const unsigned short* __restrict__ delta,
    char* __restrict__ ws)
{
  __shared__ __align__(16) unsigned short hs[2][4][1032];  // pad: row stride 2064B

  const int tid  = threadIdx.x;
  const int lane = tid & 63;
  const int wv   = tid >> 6;
  const int l15  = lane & 15, lhi = lane >> 4;
  const int g     = blockIdx.x & 7;
  const int chunk = blockIdx.x >> 3;

  char* reg = ws + WS_SYNC_OFF + (size_t)g * GRP_STRIDE;
  unsigned short* Lbuf  = (unsigned short*)reg;
  unsigned int*   Lflag = (unsigned int*)(reg + LFLAG_OFF);
  unsigned short* Gbuf  = (unsigned short*)(reg + GBUF_OFF);
  unsigned int*   Gflag = (unsigned int*)(reg + GFLAG_OFF);

  const int cb = chunk * 128 + wv * 32;     // this wave's 32 output cols
  const int bl = l15 & 3;                   // batch-local (lanes 4-15 duplicate)
  const int b  = g * 4 + bl;
  const int j0[2] = { cb + lhi * 4, cb + 16 + lhi * 4 };
  const bool valid = (l15 < 4);

  // R fragments as A-operand (r4-verified transposed-MFMA layout):
  // ra[nt][kt] = R[cb+nt*16+l15][kt*32+lhi*8 .. +7]
  bf16x8 ra[2][32];
  #pragma unroll
  for (int nt = 0; nt < 2; ++nt) {
    const float* rrow = R + (size_t)(cb + nt * 16 + l15) * 1024 + lhi * 8;
    #pragma unroll
    for (int kt = 0; kt < 32; ++kt) {
      float4 u0 = *(const float4*)(rrow + kt * 32);
      float4 u1 = *(const float4*)(rrow + kt * 32 + 4);
      ra[nt][kt] = pack8(u0, u1);
    }
  }

  // h state (all lanes compute batch bl; only l15<4 store)
  float hloc[2][4];
  #pragma unroll
  for (int nt = 0; nt < 2; ++nt) {
    const f32x4 hv = *(const f32x4*)(h0 + (size_t)b * 1024 + j0[nt]);
    #pragma unroll
    for (int r = 0; r < 4; ++r) hloc[nt][r] = hv[r];
  }

  // initial publish of h0 into parity-0 (both paths), flags = 1
  if (valid) {
    #pragma unroll
    for (int nt = 0; nt < 2; ++nt) {
      const unsigned long long pk =
          pack4bf(hloc[nt][0], hloc[nt][1], hloc[nt][2], hloc[nt][3]);
      st8_loc(Lbuf + bl * 1024 + j0[nt], pk);
      st8_glb(Gbuf + bl * 1024 + j0[nt], pk);
    }
  }
  asm volatile("s_waitcnt vmcnt(0)" ::: "memory");
  __syncthreads();
  if (tid == 0) { st4_loc(&Lflag[chunk], 1u); st4_glb(&Gflag[chunk], 1u); }

  // staging map: thread -> row (tid&3), 16B block (tid>>2); 2 blocks 1KB apart
  const int soff = (tid & 3) * 1024 + (tid >> 2) * 8;   // halves
  int gmode = 0;

  for (int t = 0; t < 1024; ++t) {
    const int par = t & 1, npar = par ^ 1;
    float*                outp = out + (size_t)t * 32768;
    const unsigned short* dp   = delta + (size_t)t * 32768;
    const unsigned target = (unsigned)t + 1u;

    // prefetch wx / delta (plain cached; drained by poll's vmcnt)
    f32x4 wx4[2]; unsigned long long d4[2];
    #pragma unroll
    for (int nt = 0; nt < 2; ++nt) {
      wx4[nt] = *(const f32x4*)(outp + (size_t)b * 1024 + j0[nt]);
      d4[nt]  = *(const unsigned long long*)(dp + (size_t)b * 1024 + j0[nt]);
    }

    // poll local flags (bounded), fall back to global flags (producer-live)
    if (!gmode) {
      int it = 0;
      for (;;) {
        u32x4 fa, fb;
        asm volatile(
          "global_load_dwordx4 %0, %2, off sc0\n\t"
          "global_load_dwordx4 %1, %2, off offset:16 sc0\n\t"
          "s_waitcnt vmcnt(0)"
          : "=&v"(fa), "=&v"(fb) : "v"(Lflag) : "memory");
        unsigned m = fa[0];
        #pragma unroll
        for (int q = 1; q < 4; ++q) m = fa[q] < m ? fa[q] : m;
        #pragma unroll
        for (int q = 0; q < 4; ++q) m = fb[q] < m ? fb[q] : m;
        if (m >= target) break;
        if (++it >= SPIN_LIMIT) { gmode = 1; break; }
      }
    }
    if (gmode) {
      for (;;) {
        u32x4 fa, fb;
        asm volatile(
          "global_load_dwordx4 %0, %2, off sc0 sc1\n\t"
          "global_load_dwordx4 %1, %2, off offset:16 sc0 sc1\n\t"
          "s_waitcnt vmcnt(0)"
          : "=&v"(fa), "=&v"(fb) : "v"(Gflag) : "memory");
        unsigned m = fa[0];
        #pragma unroll
        for (int q = 1; q < 4; ++q) m = fa[q] < m ? fa[q] : m;
        #pragma unroll
        for (int q = 0; q < 4; ++q) m = fb[q] < m ? fb[q] : m;
        if (m >= target) break;
      }
    }

    // stage my 32B of the 8KB h-slab (serial after flag pass -> race-free)
    f32x4 s0, s1;
    if (!gmode) {
      const unsigned short* sp = Lbuf + par * 4096 + soff;
      asm volatile(
        "global_load_dwordx4 %0, %2, off sc0\n\t"
        "global_load_dwordx4 %1, %2, off offset:1024 sc0\n\t"
        "s_waitcnt vmcnt(0)"
        : "=&v"(s0), "=&v"(s1) : "v"(sp) : "memory");
    } else {
      const unsigned short* sp = Gbuf + par * 4096 + soff;
      asm volatile(
        "global_load_dwordx4 %0, %2, off sc0 sc1\n\t"
        "global_load_dwordx4 %1, %2, off offset:1024 sc0 sc1\n\t"
        "s_waitcnt vmcnt(0)"
        : "=&v"(s0), "=&v"(s1) : "v"(sp) : "memory");
    }
    __builtin_amdgcn_sched_barrier(0);
    *(f32x4*)&hs[par][tid & 3][(tid >> 2) * 8]       = s0;
    *(f32x4*)&hs[par][tid & 3][(tid >> 2) * 8 + 512] = s1;
    __syncthreads();

    // y^T = R_chunk @ h^T   (B-frag: row = batch bl, k = kt*32+lhi*8)
    f32x4 acc[2][4] = {};
    #pragma unroll
    for (int kt = 0; kt < 32; ++kt) {
      const bf16x8 a = *(const bf16x8*)&hs[par][bl][kt * 32 + lhi * 8];
      acc[0][kt & 3] = mfma16(ra[0][kt], a, acc[0][kt & 3]);
      acc[1][kt & 3] = mfma16(ra[1][kt], a, acc[1][kt & 3]);
    }

    // blend
    f32x4 o[2]; unsigned long long pk[2];
    #pragma unroll
    for (int nt = 0; nt < 2; ++nt) {
      const f32x4 y = (acc[nt][0] + acc[nt][1]) + (acc[nt][2] + acc[nt][3]) + wx4[nt];
      #pragma unroll
      for (int r = 0; r < 4; ++r) {
        const float c = fast_tanh(y[r]);
        const float d = bf2f((unsigned short)(d4[nt] >> (16 * r)));
        const float h = hloc[nt][r];
        const float v = fmaf(d, c - h, h);
        hloc[nt][r] = v;
        o[nt][r] = v;
      }
      pk[nt] = pack4bf(o[nt][0], o[nt][1], o[nt][2], o[nt][3]);
    }

    // publish LOCAL first (critical path): data -> drain -> barrier -> flag
    if (valid) {
      st8_loc(Lbuf + npar * 4096 + bl * 1024 + j0[0], pk[0]);
      st8_loc(Lbuf + npar * 4096 + bl * 1024 + j0[1], pk[1]);
    }
    asm volatile("s_waitcnt vmcnt(0)" ::: "memory");
    __syncthreads();
    if (tid == 0) st4_loc(&Lflag[chunk], (unsigned)t + 2u);

    // publish GLOBAL mirror (off critical path, keeps fallback live)
    if (valid) {
      st8_glb(Gbuf + npar * 4096 + bl * 1024 + j0[0], pk[0]);
      st8_glb(Gbuf + npar * 4096 + bl * 1024 + j0[1], pk[1]);
    }
    asm volatile("s_waitcnt vmcnt(0)" ::: "memory");
    __syncthreads();
    if (tid == 0) st4_glb(&Gflag[chunk], (unsigned)t + 2u);

    // fat fp32 out stores last
    if (valid) {
      *(f32x4*)(outp + (size_t)b * 1024 + j0[0]) = o[0];
      *(f32x4*)(outp + (size_t)b * 1024 + j0[1]) = o[1];
    }
  }
}

// ---------------------------------------------------------------------------
extern "C" void kernel_launch(void* const* d_in, const int* in_sizes, int n_in,
                              void* d_out, int out_size, void* d_ws, size_t ws_size,
                              hipStream_t stream) {
  const float* x    = (const float*)d_in[0];
  const float* h0   = (const float*)d_in[1];
  const float* Wx   = (const float*)d_in[2];
  const float* R    = (const float*)d_in[3];
  const float* bias = (const float*)d_in[4];
  const float* Wd   = (const float*)d_in[5];
  const float* bd   = (const float*)d_in[6];
  float* out = (float*)d_out;

  // ws: [0,64MiB) delta bf16; [64MiB, +258KiB) sync region (8 x 33024B).
  unsigned short* delta_ws = (unsigned short*)d_ws;
  char* ws = (char*)d_ws;

  hipMemsetAsync(ws + WS_SYNC_OFF, 0, 8 * GRP_STRIDE, stream);

  dim3 pg(256, 16);
  proj_kernel<<<pg, 256, 0, stream>>>(x, Wx, Wd, bias, bd, out, delta_ws);
  rnn_kernel<<<64, 256, 0, stream>>>(R, h0, out, delta_ws, ws);
}

// Round 10
// 5930.159 us; speedup vs baseline: 1.3119x; 1.0462x over previous
//
#include <hip/hip_runtime.h>
#include <stdint.h>

// T=1024, B=32, D=H=1024.  M = T*B = 32768.
typedef float  f32x4  __attribute__((ext_vector_type(4)));
typedef short  bf16x8 __attribute__((ext_vector_type(8)));
typedef unsigned int u32x4 __attribute__((ext_vector_type(4)));

__device__ __forceinline__ unsigned short f2bf(float f) {
  union { float f; unsigned u; } v; v.f = f;
  unsigned r = v.u + 0x7fffu + ((v.u >> 16) & 1u);   // RNE, inputs are finite
  return (unsigned short)(r >> 16);
}
__device__ __forceinline__ float bf2f(unsigned short s) {
  union { unsigned u; float f; } v; v.u = ((unsigned)s) << 16; return v.f;
}
__device__ __forceinline__ bf16x8 pack8(float4 a, float4 b) {
  bf16x8 v;
  v[0]=(short)f2bf(a.x); v[1]=(short)f2bf(a.y); v[2]=(short)f2bf(a.z); v[3]=(short)f2bf(a.w);
  v[4]=(short)f2bf(b.x); v[5]=(short)f2bf(b.y); v[6]=(short)f2bf(b.z); v[7]=(short)f2bf(b.w);
  return v;
}
__device__ __forceinline__ unsigned long long pack4bf(float a, float b, float c, float d) {
  return (unsigned long long)f2bf(a) | ((unsigned long long)f2bf(b) << 16)
       | ((unsigned long long)f2bf(c) << 32) | ((unsigned long long)f2bf(d) << 48);
}
__device__ __forceinline__ f32x4 mfma16(bf16x8 a, bf16x8 b, f32x4 c) {
  return __builtin_amdgcn_mfma_f32_16x16x32_bf16(a, b, c, 0, 0, 0);
}
// fast tanh: 1 - 2/(exp(2y)+1); v_exp/v_rcp are ~1ulp, saturates correctly.
__device__ __forceinline__ float fast_tanh(float y) {
  return 1.0f - 2.0f * __builtin_amdgcn_rcpf(__expf(2.0f * y) + 1.0f);
}

// ---------------------------------------------------------------------------
// Phase 1 (unchanged, known-good): wx = x@Wx^T + bias -> d_out (fp32);
// delta = sigmoid(x@Wd^T + b_delta) -> ws (bf16).
// ---------------------------------------------------------------------------
__global__ __launch_bounds__(256) void proj_kernel(
    const float* __restrict__ x,  const float* __restrict__ Wx,
    const float* __restrict__ Wd, const float* __restrict__ bias,
    const float* __restrict__ bd, float* __restrict__ wx_out,
    unsigned short* __restrict__ delta_out)
{
  __shared__ __align__(16) unsigned short lA[128 * 40];
  __shared__ __align__(16) unsigned short lB[128 * 40];

  const int tid  = threadIdx.x;
  const int lane = tid & 63;
  const int wv   = tid >> 6;
  const int wm   = (wv >> 1) * 64;
  const int wn   = (wv & 1) * 64;
  const int l15  = lane & 15, lhi = lane >> 4;

  const int  bm    = blockIdx.x;
  const int  bn    = blockIdx.y;
  const bool isd   = bn >= 8;
  const float* W   = isd ? Wd : Wx;
  const int  ncol0 = (bn & 7) * 128;
  const int  row0  = bm * 128;

  const int srow = tid >> 1;
  const int scol = (tid & 1) * 16;

  f32x4 acc[4][4] = {};

  for (int k0 = 0; k0 < 1024; k0 += 32) {
    const float* pa = x + (size_t)(row0 + srow) * 1024 + (k0 + scol);
    const float* pb = W + (size_t)(ncol0 + srow) * 1024 + (k0 + scol);
    float4 a0 = *(const float4*)(pa + 0), a1 = *(const float4*)(pa + 4);
    float4 a2 = *(const float4*)(pa + 8), a3 = *(const float4*)(pa + 12);
    float4 b0 = *(const float4*)(pb + 0), b1 = *(const float4*)(pb + 4);
    float4 b2 = *(const float4*)(pb + 8), b3 = *(const float4*)(pb + 12);

    *(bf16x8*)&lA[srow * 40 + scol]     = pack8(a0, a1);
    *(bf16x8*)&lA[srow * 40 + scol + 8] = pack8(a2, a3);
    *(bf16x8*)&lB[srow * 40 + scol]     = pack8(b0, b1);
    *(bf16x8*)&lB[srow * 40 + scol + 8] = pack8(b2, b3);
    __syncthreads();

    bf16x8 af[4], bfr[4];
    #pragma unroll
    for (int i = 0; i < 4; ++i) {
      af[i]  = *(const bf16x8*)&lA[(wm + i * 16 + l15) * 40 + lhi * 8];
      bfr[i] = *(const bf16x8*)&lB[(wn + i * 16 + l15) * 40 + lhi * 8];
    }
    #pragma unroll
    for (int i = 0; i < 4; ++i)
      #pragma unroll
      for (int j = 0; j < 4; ++j)
        acc[i][j] = mfma16(af[i], bfr[j], acc[i][j]);
    __syncthreads();
  }

  #pragma unroll
  for (int i = 0; i < 4; ++i) {
    const int rbase = row0 + wm + i * 16 + lhi * 4;
    #pragma unroll
    for (int j = 0; j < 4; ++j) {
      const int col = ncol0 + wn + j * 16 + l15;
      #pragma unroll
      for (int r = 0; r < 4; ++r) {
        const size_t idx = (size_t)(rbase + r) * 1024 + col;
        const float v = acc[i][j][r];
        if (!isd) {
          wx_out[idx] = v + bias[col];
        } else {
          const float s = 1.0f / (1.0f + expf(-(v + bd[col])));
          delta_out[idx] = f2bf(s);
        }
      }
    }
  }
}

// ---------------------------------------------------------------------------
// Phase 2: persistent recurrence, r4 skeleton + decontended sync.
// grid = 16 WGs x 256 thr: blockIdx = bg*8 + chunk (bg = batch group of 16).
// y^T = R @ h^T: R = A-operand (reg-resident ra[2][32]); h staged per step
// (256 thr x 128B coherent dwordx4) -> XOR-swizzled double-buffered LDS.
// Sync (all sc0sc1, the only channel that has ever been both correct AND
// non-hanging here; sc0-only XCD-local signaling hung 3 rounds, banned):
//   flags: 8 lines/bg (one per WG; dwords 0..3 = its 4 waves).  Producer
//   wave: h stores + out stores -> ONE vmcnt(0) -> lane0 flag=t+2.
//   Poll: ONLY wave 0 of each WG polls the 8 lines (min over 32 flags),
//   then releases waves 1-3 via an LDS word (workgroup-scope atomic).
//   8 fabric pollers/bg instead of 32; producer stores spread over 8 lines.
// ---------------------------------------------------------------------------
__global__ __launch_bounds__(256, 1) void rnn_kernel(
    const float* __restrict__ R, const float* __restrict__ h0,
    float* __restrict__ out, const unsigned short* __restrict__ delta,
    unsigned short* __restrict__ hbuf, unsigned int* __restrict__ flags_all)
{
  __shared__ __align__(16) unsigned short hs[2][16384];   // 2 x 32KB
  __shared__ unsigned step_rdy;

  const int tid  = threadIdx.x;
  const int lane = tid & 63;
  const int wv   = tid >> 6;
  const int l15  = lane & 15, lhi = lane >> 4;
  const int chunk = blockIdx.x & 7;
  const int bg    = blockIdx.x >> 3;
  const int B0    = bg * 16;
  const int cb    = chunk * 128 + wv * 32;
  unsigned int* flags = flags_all + bg * 256;          // 1KB (8 x 128B lines)
  unsigned int* fslot = flags + chunk * 32 + wv;       // own line, own dword

  // R fragments as A-operand: ra[nt][kt] = R[j=cb+nt*16+l15][kt*32+lhi*8 ..+7]
  bf16x8 ra[2][32];
  #pragma unroll
  for (int nt = 0; nt < 2; ++nt) {
    const float* rrow = R + (size_t)(cb + nt * 16 + l15) * 1024 + lhi * 8;
    #pragma unroll
    for (int kt = 0; kt < 32; ++kt) {
      float4 u0 = *(const float4*)(rrow + kt * 32);
      float4 u1 = *(const float4*)(rrow + kt * 32 + 4);
      ra[nt][kt] = pack8(u0, u1);
    }
  }

  const int b = B0 + l15;                       // this lane's batch (C-col)
  const int j0[2] = { cb + lhi * 4, cb + 16 + lhi * 4 };

  if (tid == 0) step_rdy = 0;

  // init h + publish into parity-0 buffer
  float hloc[2][4];
  #pragma unroll
  for (int nt = 0; nt < 2; ++nt) {
    const f32x4 hv = *(const f32x4*)(h0 + (size_t)b * 1024 + j0[nt]);
    hloc[nt][0] = hv[0]; hloc[nt][1] = hv[1];
    hloc[nt][2] = hv[2]; hloc[nt][3] = hv[3];
    asm volatile("global_store_dwordx2 %0, %1, off sc0 sc1"
                 :: "v"(hbuf + (size_t)b * 1024 + j0[nt]),
                    "v"(pack4bf(hv[0], hv[1], hv[2], hv[3])) : "memory");
  }
  asm volatile("s_waitcnt vmcnt(0)" ::: "memory");
  __syncthreads();                               // also covers step_rdy init
  if (lane == 0)
    asm volatile("global_store_dword %0, %1, off sc0 sc1"
                 :: "v"(fslot), "v"(1u) : "memory");

  // staging map: thread i -> row (i&15), 128B col-block (i>>4)
  const int lrow = tid & 15, cblk = tid >> 4;
  const size_t gstage = (size_t)(B0 + lrow) * 1024 + cblk * 64;   // halves
  int swz[8];
  #pragma unroll
  for (int m = 0; m < 8; ++m)
    swz[m] = lrow * 2048 + ((cblk * 128 + m * 16) ^ ((lrow & 7) << 4));

  const int rbase_l = l15 * 2048;
  const int rxor    = (l15 & 7) << 4;

  for (int t = 0; t < 1024; ++t) {
    const unsigned short* hin  = hbuf + (t & 1) * 32768;
    unsigned short*       hout = hbuf + ((t & 1) ^ 1) * 32768;
    float*                outp = out + (size_t)t * 32768;
    const unsigned short* dp   = delta + (size_t)t * 32768;
    const unsigned target = (unsigned)t + 1u;

    // Prefetch wx / delta (plain cached loads; overlap with the wait).
    f32x4 wx4[2]; unsigned long long d4[2];
    #pragma unroll
    for (int nt = 0; nt < 2; ++nt) {
      wx4[nt] = *(const f32x4*)(outp + (size_t)b * 1024 + j0[nt]);
      d4[nt]  = *(const unsigned long long*)(dp + (size_t)b * 1024 + j0[nt]);
    }

    // Wait for all 32 waves of this bg: wave 0 polls fabric, others poll LDS.
    if (wv == 0) {
      for (;;) {
        u32x4 f0, f1, f2, f3, f4, f5, f6, f7;
        asm volatile(
          "global_load_dwordx4 %0, %8, off sc0 sc1\n\t"
          "global_load_dwordx4 %1, %8, off offset:128 sc0 sc1\n\t"
          "global_load_dwordx4 %2, %8, off offset:256 sc0 sc1\n\t"
          "global_load_dwordx4 %3, %8, off offset:384 sc0 sc1\n\t"
          "global_load_dwordx4 %4, %8, off offset:512 sc0 sc1\n\t"
          "global_load_dwordx4 %5, %8, off offset:640 sc0 sc1\n\t"
          "global_load_dwordx4 %6, %8, off offset:768 sc0 sc1\n\t"
          "global_load_dwordx4 %7, %8, off offset:896 sc0 sc1\n\t"
          "s_waitcnt vmcnt(0)"
          : "=&v"(f0), "=&v"(f1), "=&v"(f2), "=&v"(f3),
            "=&v"(f4), "=&v"(f5), "=&v"(f6), "=&v"(f7)
          : "v"(flags)
          : "memory");
        unsigned m = f0[0];
        #pragma unroll
        for (int q = 1; q < 4; ++q) m = f0[q] < m ? f0[q] : m;
        #pragma unroll
        for (int q = 0; q < 4; ++q) {
          m = f1[q] < m ? f1[q] : m;  m = f2[q] < m ? f2[q] : m;
          m = f3[q] < m ? f3[q] : m;  m = f4[q] < m ? f4[q] : m;
          m = f5[q] < m ? f5[q] : m;  m = f6[q] < m ? f6[q] : m;
          m = f7[q] < m ? f7[q] : m;
        }
        if (m >= target) break;
      }
      if (lane == 0)
        __hip_atomic_store(&step_rdy, target, __ATOMIC_RELAXED,
                           __HIP_MEMORY_SCOPE_WORKGROUP);
    } else {
      while (__hip_atomic_load(&step_rdy, __ATOMIC_RELAXED,
                               __HIP_MEMORY_SCOPE_WORKGROUP) < target) {}
    }

    // Stage 128B of h: 8 back-to-back coherent loads, ONE latency.
    const unsigned short* gp = hin + gstage;
    f32x4 s0, s1, s2, s3, s4, s5, s6, s7;
    asm volatile(
      "global_load_dwordx4 %0, %8, off sc0 sc1\n\t"
      "global_load_dwordx4 %1, %8, off offset:16 sc0 sc1\n\t"
      "global_load_dwordx4 %2, %8, off offset:32 sc0 sc1\n\t"
      "global_load_dwordx4 %3, %8, off offset:48 sc0 sc1\n\t"
      "global_load_dwordx4 %4, %8, off offset:64 sc0 sc1\n\t"
      "global_load_dwordx4 %5, %8, off offset:80 sc0 sc1\n\t"
      "global_load_dwordx4 %6, %8, off offset:96 sc0 sc1\n\t"
      "global_load_dwordx4 %7, %8, off offset:112 sc0 sc1"
      : "=&v"(s0), "=&v"(s1), "=&v"(s2), "=&v"(s3),
        "=&v"(s4), "=&v"(s5), "=&v"(s6), "=&v"(s7)
      : "v"(gp)
      : "memory");
    asm volatile("s_waitcnt vmcnt(0)" ::: "memory");
    __builtin_amdgcn_sched_barrier(0);

    char* lb = (char*)&hs[t & 1][0];
    *(f32x4*)(lb + swz[0]) = s0;  *(f32x4*)(lb + swz[1]) = s1;
    *(f32x4*)(lb + swz[2]) = s2;  *(f32x4*)(lb + swz[3]) = s3;
    *(f32x4*)(lb + swz[4]) = s4;  *(f32x4*)(lb + swz[5]) = s5;
    *(f32x4*)(lb + swz[6]) = s6;  *(f32x4*)(lb + swz[7]) = s7;
    __syncthreads();

    // y^T = R_chunk @ h^T  (B-frags from LDS, 4-way acc rotation)
    const char* lr = lb + rbase_l;
    f32x4 acc[2][4] = {};
    #pragma unroll
    for (int kt = 0; kt < 32; ++kt) {
      const bf16x8 a = *(const bf16x8*)(lr + ((kt * 64 + lhi * 16) ^ rxor));
      acc[0][kt & 3] = mfma16(ra[0][kt], a, acc[0][kt & 3]);
      acc[1][kt & 3] = mfma16(ra[1][kt], a, acc[1][kt & 3]);
    }

    // blend; publish h + out stores -> ONE drain -> own flag.
    f32x4 o[2];
    #pragma unroll
    for (int nt = 0; nt < 2; ++nt) {
      const f32x4 y = (acc[nt][0] + acc[nt][1]) + (acc[nt][2] + acc[nt][3]) + wx4[nt];
      #pragma unroll
      for (int r = 0; r < 4; ++r) {
        const float c = fast_tanh(y[r]);
        const float d = bf2f((unsigned short)(d4[nt] >> (16 * r)));
        const float h = hloc[nt][r];
        const float v = fmaf(d, c - h, h);
        hloc[nt][r] = v;
        o[nt][r] = v;
      }
      asm volatile("global_store_dwordx2 %0, %1, off sc0 sc1"
                   :: "v"(hout + (size_t)b * 1024 + j0[nt]),
                      "v"(pack4bf(o[nt][0], o[nt][1], o[nt][2], o[nt][3])) : "memory");
      *(f32x4*)(outp + (size_t)b * 1024 + j0[nt]) = o[nt];
    }
    asm volatile("s_waitcnt vmcnt(0)" ::: "memory");   // h + out acks, parallel
    if (lane == 0)
      asm volatile("global_store_dword %0, %1, off sc0 sc1"
                   :: "v"(fslot), "v"((unsigned)t + 2u) : "memory");
  }
}

// ---------------------------------------------------------------------------
extern "C" void kernel_launch(void* const* d_in, const int* in_sizes, int n_in,
                              void* d_out, int out_size, void* d_ws, size_t ws_size,
                              hipStream_t stream) {
  const float* x    = (const float*)d_in[0];
  const float* h0   = (const float*)d_in[1];
  const float* Wx   = (const float*)d_in[2];
  const float* R    = (const float*)d_in[3];
  const float* bias = (const float*)d_in[4];
  const float* Wd   = (const float*)d_in[5];
  const float* bd   = (const float*)d_in[6];
  float* out = (float*)d_out;

  // ws layout: [0,64MiB) delta bf16; [64MiB,+128KiB) hbuf (2x 32x1024 bf16);
  // flags at 64MiB+256KiB (2 bgs x 1KiB), zeroed in-graph each launch.
  unsigned short* delta_ws = (unsigned short*)d_ws;
  unsigned short* hbuf     = delta_ws + (size_t)32768 * 1024;
  unsigned int*   flags    = (unsigned int*)((char*)d_ws + 64ull * 1024 * 1024 + 256 * 1024);

  hipMemsetAsync(flags, 0, 2048, stream);

  dim3 pg(256, 16);
  proj_kernel<<<pg, 256, 0, stream>>>(x, Wx, Wd, bias, bd, out, delta_ws);
  rnn_kernel<<<16, 256, 0, stream>>>(R, h0, out, delta_ws, hbuf, flags);
}